// Round 1
// baseline (522.698 us; speedup 1.0000x reference)
//
#include <hip/hip_runtime.h>
#include <stdint.h>

#define BSZ   16
#define LSEQ  4096
#define HDIM  128
#define PDIM  256
#define BLROWS (BSZ*LSEQ)      // 65536
#define CHUNKS 64
#define TCH   (LSEQ/CHUNKS)    // 64 == 2^6

// ---------------- workspace layout (bytes) ----------------
constexpr size_t WS_COEF  = 0;                                    // 6*PDIM floats (mA,mB,mC,mD,dts,f1)
constexpr size_t WS_MPOW  = 8192;                                 // 4*PDIM floats (M^64)
constexpr size_t WS_F1    = 16384;                                // BLROWS*PDIM ushort2 (64 MB)
constexpr size_t WS_XS    = WS_F1 + (size_t)BLROWS*PDIM*4;        // BLROWS*PDIM ushort2 (64 MB)
constexpr size_t WS_ENDS  = WS_XS + (size_t)BLROWS*PDIM*4;        // BSZ*CHUNKS*PDIM float4 (4 MB)
constexpr size_t WS_CARRY = WS_ENDS + (size_t)BSZ*CHUNKS*PDIM*16; // 4 MB

__device__ __forceinline__ unsigned short f2bf(float f) {
  unsigned u = __float_as_uint(f);
  u = (u + 0x7fffu + ((u >> 16) & 1u)) >> 16;   // RNE
  return (unsigned short)u;
}
__device__ __forceinline__ float bf2f(unsigned short s) {
  return __uint_as_float(((unsigned)s) << 16);
}

// ---------------- K1: per-p coefficients + M^64 ----------------
__global__ void coeff_kernel(const float* __restrict__ A_diag,
                             const float* __restrict__ G_diag,
                             const float* __restrict__ dtp,
                             float* __restrict__ coef,
                             float* __restrict__ mpow) {
  int p = threadIdx.x;
  float dt_s = 1.0f / (1.0f + expf(-dtp[p]));
  float A = fmaxf(A_diag[p], 0.0f);
  float G = fmaxf(G_diag[p], 0.0f);
  float root  = sqrtf(1.0f + dt_s * G);
  float denom = fmaxf(dt_s * dt_s, 1e-6f);
  float A_low  = (2.0f + dt_s * G - 2.0f * root) / denom;
  float A_high = (2.0f + dt_s * G + 2.0f * root) / denom;
  A = A_low + fmaxf(A - A_low, 0.0f) - fmaxf(A - A_high, 0.0f);
  float S  = 1.0f / (1.0f + dt_s * G);
  float mA = S;
  float mB = -A * dt_s * S;
  float mC = dt_s * S;
  float mD = 1.0f - A * dt_s * dt_s * S;
  coef[0*PDIM + p] = mA;
  coef[1*PDIM + p] = mB;
  coef[2*PDIM + p] = mC;
  coef[3*PDIM + p] = mD;
  coef[4*PDIM + p] = dt_s;
  coef[5*PDIM + p] = mC;   // f1 scale = dt_s*S == mC
  // M^64 via 6 squarings
  float a = mA, b = mB, c = mC, d = mD;
  #pragma unroll
  for (int i = 0; i < 6; i++) {
    float na = a*a + b*c, nb = a*b + b*d, nc = c*a + d*c, nd = c*b + d*d;
    a = na; b = nb; c = nc; d = nd;
  }
  mpow[0*PDIM + p] = a;
  mpow[1*PDIM + p] = b;
  mpow[2*PDIM + p] = c;
  mpow[3*PDIM + p] = d;
}

// ---------------- K2: F1[bl][p] = f1c[p] * (u[bl] . B[p]) (re,im), bf16 ----------------
// block: 256 threads (one per p), 16 rows per block
__global__ __launch_bounds__(256) void bu_kernel(const float* __restrict__ u,
                                                 const float* __restrict__ B,
                                                 const float* __restrict__ coef,
                                                 ushort2* __restrict__ F1) {
  __shared__ float xs[16][HDIM];   // 8 KB
  int t = threadIdx.x;
  int bl0 = blockIdx.x * 16;
  // stage 16 input rows
  const float4* usrc = (const float4*)(u + (size_t)bl0 * HDIM);
  float4* xd = (float4*)&xs[0][0];
  xd[t]       = usrc[t];
  xd[t + 256] = usrc[t + 256];
  __syncthreads();

  int p = t;
  float accre[16], accim[16];
  #pragma unroll
  for (int r = 0; r < 16; r++) { accre[r] = 0.0f; accim[r] = 0.0f; }

  const float4* Bp = (const float4*)(B + (size_t)p * 2 * HDIM);  // B[p][h][c], 256 floats
  #pragma unroll 2
  for (int h4 = 0; h4 < 32; h4++) {
    float4 b4a = Bp[h4*2];      // (re h0, im h0, re h1, im h1)
    float4 b4b = Bp[h4*2 + 1];  // (re h2, im h2, re h3, im h3)
    #pragma unroll
    for (int r = 0; r < 16; r++) {
      float4 x4 = *(const float4*)&xs[r][h4*4];
      accre[r] = fmaf(x4.x,b4a.x, fmaf(x4.y,b4a.z, fmaf(x4.z,b4b.x, fmaf(x4.w,b4b.z, accre[r]))));
      accim[r] = fmaf(x4.x,b4a.y, fmaf(x4.y,b4a.w, fmaf(x4.z,b4b.y, fmaf(x4.w,b4b.w, accim[r]))));
    }
  }
  float f1 = coef[5*PDIM + p];
  #pragma unroll
  for (int r = 0; r < 16; r++) {
    F1[(size_t)(bl0 + r) * PDIM + p] = make_ushort2(f2bf(accre[r]*f1), f2bf(accim[r]*f1));
  }
}

// ---------------- K3a: per-chunk local scan (zero init), write end states ----------------
__global__ __launch_bounds__(256) void scan1_kernel(const ushort2* __restrict__ F1,
                                                    const float* __restrict__ coef,
                                                    float4* __restrict__ ends) {
  int p = threadIdx.x;
  int c = blockIdx.x, b = blockIdx.y;
  float mA = coef[p], mB = coef[PDIM+p], mC = coef[2*PDIM+p], mD = coef[3*PDIM+p], dts = coef[4*PDIM+p];
  size_t base = ((size_t)(b * LSEQ + c * TCH)) * PDIM + p;
  float v1re = 0, v1im = 0, v2re = 0, v2im = 0;
  #pragma unroll 8
  for (int tt = 0; tt < TCH; tt++) {
    ushort2 f = F1[base + (size_t)tt * PDIM];
    float fre = bf2f(f.x), fim = bf2f(f.y);
    float n1re = fmaf(mA, v1re, fmaf(mB, v2re, fre));
    float n1im = fmaf(mA, v1im, fmaf(mB, v2im, fim));
    float n2re = fmaf(mC, v1re, fmaf(mD, v2re, dts * fre));
    float n2im = fmaf(mC, v1im, fmaf(mD, v2im, dts * fim));
    v1re = n1re; v1im = n1im; v2re = n2re; v2im = n2im;
  }
  ends[((size_t)b * CHUNKS + c) * PDIM + p] = make_float4(v1re, v1im, v2re, v2im);
}

// ---------------- K3b: sequential carry combine across chunks ----------------
__global__ __launch_bounds__(256) void carry_kernel(const float4* __restrict__ ends,
                                                    const float* __restrict__ mpow,
                                                    float4* __restrict__ carries) {
  int p = threadIdx.x;
  int b = blockIdx.x;
  float qA = mpow[p], qB = mpow[PDIM+p], qC = mpow[2*PDIM+p], qD = mpow[3*PDIM+p];
  float c1re = 0, c1im = 0, c2re = 0, c2im = 0;
  #pragma unroll 4
  for (int c = 0; c < CHUNKS; c++) {
    size_t idx = ((size_t)b * CHUNKS + c) * PDIM + p;
    carries[idx] = make_float4(c1re, c1im, c2re, c2im);
    float4 e = ends[idx];
    float n1re = fmaf(qA, c1re, fmaf(qB, c2re, e.x));
    float n1im = fmaf(qA, c1im, fmaf(qB, c2im, e.y));
    float n2re = fmaf(qC, c1re, fmaf(qD, c2re, e.z));
    float n2im = fmaf(qC, c1im, fmaf(qD, c2im, e.w));
    c1re = n1re; c1im = n1im; c2re = n2re; c2im = n2im;
  }
}

// ---------------- K3c: re-scan with carry-in, emit xs = v2 (bf16 pairs) ----------------
__global__ __launch_bounds__(256) void scan2_kernel(const ushort2* __restrict__ F1,
                                                    const float* __restrict__ coef,
                                                    const float4* __restrict__ carries,
                                                    ushort2* __restrict__ xsout) {
  int p = threadIdx.x;
  int c = blockIdx.x, b = blockIdx.y;
  float mA = coef[p], mB = coef[PDIM+p], mC = coef[2*PDIM+p], mD = coef[3*PDIM+p], dts = coef[4*PDIM+p];
  size_t base = ((size_t)(b * LSEQ + c * TCH)) * PDIM + p;
  float4 cv = carries[((size_t)b * CHUNKS + c) * PDIM + p];
  float v1re = cv.x, v1im = cv.y, v2re = cv.z, v2im = cv.w;
  #pragma unroll 8
  for (int tt = 0; tt < TCH; tt++) {
    ushort2 f = F1[base + (size_t)tt * PDIM];
    float fre = bf2f(f.x), fim = bf2f(f.y);
    float n1re = fmaf(mA, v1re, fmaf(mB, v2re, fre));
    float n1im = fmaf(mA, v1im, fmaf(mB, v2im, fim));
    float n2re = fmaf(mC, v1re, fmaf(mD, v2re, dts * fre));
    float n2im = fmaf(mC, v1im, fmaf(mD, v2im, dts * fim));
    v1re = n1re; v1im = n1im; v2re = n2re; v2im = n2im;
    xsout[base + (size_t)tt * PDIM] = make_ushort2(f2bf(v2re), f2bf(v2im));
  }
}

// ---------------- K4: ys = xs_re . C0^T - xs_im . C1^T + D*u ----------------
// block: 128 threads (one per h), 16 rows per block
__global__ __launch_bounds__(128) void out_kernel(const ushort2* __restrict__ xs,
                                                  const float* __restrict__ u,
                                                  const float* __restrict__ C,
                                                  const float* __restrict__ D,
                                                  float* __restrict__ out) {
  __shared__ float lre[16][PDIM];  // 16 KB
  __shared__ float lim[16][PDIM];  // 16 KB
  int t = threadIdx.x;
  int bl0 = blockIdx.x * 16;
  // stage + unpack 16 rows of xs
  #pragma unroll 4
  for (int i = 0; i < 32; i++) {
    int e = i * 128 + t;
    int r = e >> 8, p = e & 255;
    ushort2 v = xs[(size_t)(bl0 + r) * PDIM + p];
    lre[r][p] = bf2f(v.x);
    lim[r][p] = bf2f(v.y);
  }
  __syncthreads();

  int h = t;
  float acc[16];
  #pragma unroll
  for (int j = 0; j < 16; j++) acc[j] = 0.0f;

  const float4* Ch = (const float4*)(C + (size_t)h * 2 * PDIM);  // C[h][p][c], 512 floats
  for (int p4 = 0; p4 < 64; p4++) {
    float4 c4a = Ch[p4*2];      // (C0 p0, C1 p0, C0 p1, C1 p1)
    float4 c4b = Ch[p4*2 + 1];  // (C0 p2, C1 p2, C0 p3, C1 p3)
    #pragma unroll
    for (int j = 0; j < 16; j++) {
      float4 re4 = *(const float4*)&lre[j][p4*4];
      float4 im4 = *(const float4*)&lim[j][p4*4];
      acc[j] = fmaf(re4.x, c4a.x, fmaf(-im4.x, c4a.y, acc[j]));
      acc[j] = fmaf(re4.y, c4a.z, fmaf(-im4.y, c4a.w, acc[j]));
      acc[j] = fmaf(re4.z, c4b.x, fmaf(-im4.z, c4b.y, acc[j]));
      acc[j] = fmaf(re4.w, c4b.z, fmaf(-im4.w, c4b.w, acc[j]));
    }
  }
  float Dh = D[h];
  #pragma unroll
  for (int j = 0; j < 16; j++) {
    size_t idx = (size_t)(bl0 + j) * HDIM + h;
    out[idx] = acc[j] + Dh * u[idx];
  }
}

extern "C" void kernel_launch(void* const* d_in, const int* in_sizes, int n_in,
                              void* d_out, int out_size, void* d_ws, size_t ws_size,
                              hipStream_t stream) {
  const float* u      = (const float*)d_in[0];
  const float* A_diag = (const float*)d_in[1];
  const float* G_diag = (const float*)d_in[2];
  const float* dt     = (const float*)d_in[3];
  const float* B      = (const float*)d_in[4];
  const float* C      = (const float*)d_in[5];
  const float* D      = (const float*)d_in[6];
  float* out = (float*)d_out;

  char* w = (char*)d_ws;
  float*   coef    = (float*)(w + WS_COEF);
  float*   mpow    = (float*)(w + WS_MPOW);
  ushort2* F1      = (ushort2*)(w + WS_F1);
  ushort2* XS      = (ushort2*)(w + WS_XS);
  float4*  ends    = (float4*)(w + WS_ENDS);
  float4*  carries = (float4*)(w + WS_CARRY);

  hipLaunchKernelGGL(coeff_kernel, dim3(1), dim3(PDIM), 0, stream, A_diag, G_diag, dt, coef, mpow);
  hipLaunchKernelGGL(bu_kernel, dim3(BLROWS/16), dim3(256), 0, stream, u, B, coef, F1);
  hipLaunchKernelGGL(scan1_kernel, dim3(CHUNKS, BSZ), dim3(256), 0, stream, F1, coef, ends);
  hipLaunchKernelGGL(carry_kernel, dim3(BSZ), dim3(256), 0, stream, ends, mpow, carries);
  hipLaunchKernelGGL(scan2_kernel, dim3(CHUNKS, BSZ), dim3(256), 0, stream, F1, coef, carries, XS);
  hipLaunchKernelGGL(out_kernel, dim3(BLROWS/16), dim3(128), 0, stream, XS, u, C, D, out);
}

// Round 2
// 223.026 us; speedup vs baseline: 2.3437x; 2.3437x over previous
//
#include <hip/hip_runtime.h>
#include <stdint.h>

#define BSZ   16
#define LSEQ  4096
#define HDIM  128
#define PDIM  256
#define BLROWS (BSZ*LSEQ)      // 65536
#define CHUNKS 64
#define TCH   (LSEQ/CHUNKS)    // 64

typedef __attribute__((ext_vector_type(4))) float f32x4;
typedef __attribute__((ext_vector_type(8))) __bf16 bf16x8;

// ---------------- workspace layout (bytes) ----------------
constexpr size_t WS_COEF  = 0;                                      // 6*PDIM floats
constexpr size_t WS_MPOW  = 8192;                                   // 4*PDIM floats
constexpr size_t WS_WB    = 16384;                                  // 65536 ushort (128 KB) frag-packed Wb
constexpr size_t WS_WC    = WS_WB + 131072;                         // 65536 ushort (128 KB) frag-packed Wc
constexpr size_t WS_F1RE  = WS_WC + 131072;                         // 32 MB
constexpr size_t WS_F1IM  = WS_F1RE + (size_t)BLROWS*PDIM*2;        // 32 MB
constexpr size_t WS_XSRE  = WS_F1IM + (size_t)BLROWS*PDIM*2;        // 32 MB
constexpr size_t WS_XSIM  = WS_XSRE + (size_t)BLROWS*PDIM*2;        // 32 MB
constexpr size_t WS_ENDS  = WS_XSIM + (size_t)BLROWS*PDIM*2;        // 4 MB
constexpr size_t WS_CARRY = WS_ENDS + (size_t)BSZ*CHUNKS*PDIM*16;   // 4 MB

__device__ __forceinline__ unsigned short f2bf(float f) {
  unsigned u = __float_as_uint(f);
  u = (u + 0x7fffu + ((u >> 16) & 1u)) >> 16;   // RNE
  return (unsigned short)u;
}
__device__ __forceinline__ float bf2f(unsigned short s) {
  return __uint_as_float(((unsigned)s) << 16);
}

// ---------------- K1: per-p coefficients + M^64 ----------------
__global__ void coeff_kernel(const float* __restrict__ A_diag,
                             const float* __restrict__ G_diag,
                             const float* __restrict__ dtp,
                             float* __restrict__ coef,
                             float* __restrict__ mpow) {
  int p = threadIdx.x;
  float dt_s = 1.0f / (1.0f + expf(-dtp[p]));
  float A = fmaxf(A_diag[p], 0.0f);
  float G = fmaxf(G_diag[p], 0.0f);
  float root  = sqrtf(1.0f + dt_s * G);
  float denom = fmaxf(dt_s * dt_s, 1e-6f);
  float A_low  = (2.0f + dt_s * G - 2.0f * root) / denom;
  float A_high = (2.0f + dt_s * G + 2.0f * root) / denom;
  A = A_low + fmaxf(A - A_low, 0.0f) - fmaxf(A - A_high, 0.0f);
  float S  = 1.0f / (1.0f + dt_s * G);
  float mA = S;
  float mB = -A * dt_s * S;
  float mC = dt_s * S;
  float mD = 1.0f - A * dt_s * dt_s * S;
  coef[0*PDIM + p] = mA;
  coef[1*PDIM + p] = mB;
  coef[2*PDIM + p] = mC;
  coef[3*PDIM + p] = mD;
  coef[4*PDIM + p] = dt_s;
  coef[5*PDIM + p] = mC;   // f1 scale = dt_s*S == mC
  float a = mA, b = mB, c = mC, d = mD;
  #pragma unroll
  for (int i = 0; i < 6; i++) {
    float na = a*a + b*c, nb = a*b + b*d, nc = c*a + d*c, nd = c*b + d*d;
    a = na; b = nb; c = nc; d = nd;
  }
  mpow[0*PDIM + p] = a;
  mpow[1*PDIM + p] = b;
  mpow[2*PDIM + p] = c;
  mpow[3*PDIM + p] = d;
}

// ---------------- K1b: pack weights in MFMA fragment order ----------------
__global__ __launch_bounds__(256) void prep_kernel(const float* __restrict__ B,
                                                   const float* __restrict__ C,
                                                   const float* __restrict__ coef,
                                                   ushort* __restrict__ Wb,
                                                   ushort* __restrict__ Wc) {
  int idx = blockIdx.x * 256 + threadIdx.x;   // 0..131071
  if (idx < 65536) {
    int e  = idx & 7;
    int l  = (idx >> 3) & 63;
    int kt = (idx >> 9) & 3;
    int ct = idx >> 11;
    int h   = kt*32 + (l >> 4)*8 + e;
    int col = ct*16 + (l & 15);
    int c = col >> 8, p = col & 255;
    float f1 = coef[5*PDIM + p];
    Wb[idx] = f2bf(B[(size_t)p*2*HDIM + h*2 + c] * f1);
  } else {
    int j  = idx - 65536;
    int e  = j & 7;
    int l  = (j >> 3) & 63;
    int kt = (j >> 9) & 15;
    int ct = j >> 13;
    int k = kt*32 + (l >> 4)*8 + e;
    int h = ct*16 + (l & 15);
    int c = k >> 8, p = k & 255;
    float v = C[(size_t)h*2*PDIM + p*2 + c];
    Wc[j] = f2bf(c ? -v : v);
  }
}

// ---------------- K2: F1 = (u . B^T) * f1  via MFMA ----------------
__global__ __launch_bounds__(256) void bu_mfma(const float* __restrict__ u,
                                               const ushort* __restrict__ Wb,
                                               ushort* __restrict__ F1re,
                                               ushort* __restrict__ F1im) {
  int tid = threadIdx.x;
  int l = tid & 63, w = tid >> 6;
  int lr = l & 15, lk = l >> 4;
  int row0 = blockIdx.x * 32;

  f32x4 acc[2][8];
  #pragma unroll
  for (int rt = 0; rt < 2; rt++)
    #pragma unroll
    for (int ct = 0; ct < 8; ct++)
      acc[rt][ct] = (f32x4){0.f, 0.f, 0.f, 0.f};

  #pragma unroll
  for (int kt = 0; kt < 4; kt++) {
    bf16x8 afrag[2];
    #pragma unroll
    for (int rt = 0; rt < 2; rt++) {
      const float* ap = u + (size_t)(row0 + rt*16 + lr) * HDIM + kt*32 + lk*8;
      float4 f0 = *(const float4*)ap;
      float4 f1v = *(const float4*)(ap + 4);
      bf16x8 a;
      a[0] = (__bf16)f0.x;  a[1] = (__bf16)f0.y;  a[2] = (__bf16)f0.z;  a[3] = (__bf16)f0.w;
      a[4] = (__bf16)f1v.x; a[5] = (__bf16)f1v.y; a[6] = (__bf16)f1v.z; a[7] = (__bf16)f1v.w;
      afrag[rt] = a;
    }
    #pragma unroll
    for (int ct = 0; ct < 8; ct++) {
      int ctg = w*8 + ct;
      bf16x8 b = *(const bf16x8*)(Wb + ((size_t)(ctg*4 + kt)*64 + l)*8);
      acc[0][ct] = __builtin_amdgcn_mfma_f32_16x16x32_bf16(afrag[0], b, acc[0][ct], 0, 0, 0);
      acc[1][ct] = __builtin_amdgcn_mfma_f32_16x16x32_bf16(afrag[1], b, acc[1][ct], 0, 0, 0);
    }
  }

  #pragma unroll
  for (int rt = 0; rt < 2; rt++) {
    #pragma unroll
    for (int ct = 0; ct < 8; ct++) {
      int col = w*128 + ct*16 + lr;
      ushort* dst = (col >= 256) ? F1im : F1re;
      int p = col & 255;
      int r0 = row0 + rt*16 + lk*4;
      f32x4 a = acc[rt][ct];
      #pragma unroll
      for (int r = 0; r < 4; r++)
        dst[(size_t)(r0 + r)*PDIM + p] = f2bf(a[r]);
    }
  }
}

// ---------------- K3a: per-chunk local scan ----------------
__global__ __launch_bounds__(256) void scan1_kernel(const ushort* __restrict__ F1re,
                                                    const ushort* __restrict__ F1im,
                                                    const float* __restrict__ coef,
                                                    float4* __restrict__ ends) {
  int p = threadIdx.x;
  int c = blockIdx.x, b = blockIdx.y;
  float mA = coef[p], mB = coef[PDIM+p], mC = coef[2*PDIM+p], mD = coef[3*PDIM+p], dts = coef[4*PDIM+p];
  size_t base = ((size_t)(b * LSEQ + c * TCH)) * PDIM + p;
  float v1re = 0, v1im = 0, v2re = 0, v2im = 0;
  #pragma unroll 8
  for (int tt = 0; tt < TCH; tt++) {
    float fre = bf2f(F1re[base + (size_t)tt * PDIM]);
    float fim = bf2f(F1im[base + (size_t)tt * PDIM]);
    float n1re = fmaf(mA, v1re, fmaf(mB, v2re, fre));
    float n1im = fmaf(mA, v1im, fmaf(mB, v2im, fim));
    float n2re = fmaf(mC, v1re, fmaf(mD, v2re, dts * fre));
    float n2im = fmaf(mC, v1im, fmaf(mD, v2im, dts * fim));
    v1re = n1re; v1im = n1im; v2re = n2re; v2im = n2im;
  }
  ends[((size_t)b * CHUNKS + c) * PDIM + p] = make_float4(v1re, v1im, v2re, v2im);
}

// ---------------- K3b: carry combine ----------------
__global__ __launch_bounds__(256) void carry_kernel(const float4* __restrict__ ends,
                                                    const float* __restrict__ mpow,
                                                    float4* __restrict__ carries) {
  int p = threadIdx.x;
  int b = blockIdx.x;
  float qA = mpow[p], qB = mpow[PDIM+p], qC = mpow[2*PDIM+p], qD = mpow[3*PDIM+p];
  float c1re = 0, c1im = 0, c2re = 0, c2im = 0;
  #pragma unroll 4
  for (int c = 0; c < CHUNKS; c++) {
    size_t idx = ((size_t)b * CHUNKS + c) * PDIM + p;
    carries[idx] = make_float4(c1re, c1im, c2re, c2im);
    float4 e = ends[idx];
    float n1re = fmaf(qA, c1re, fmaf(qB, c2re, e.x));
    float n1im = fmaf(qA, c1im, fmaf(qB, c2im, e.y));
    float n2re = fmaf(qC, c1re, fmaf(qD, c2re, e.z));
    float n2im = fmaf(qC, c1im, fmaf(qD, c2im, e.w));
    c1re = n1re; c1im = n1im; c2re = n2re; c2im = n2im;
  }
}

// ---------------- K3c: re-scan with carry, emit xs planes ----------------
__global__ __launch_bounds__(256) void scan2_kernel(const ushort* __restrict__ F1re,
                                                    const ushort* __restrict__ F1im,
                                                    const float* __restrict__ coef,
                                                    const float4* __restrict__ carries,
                                                    ushort* __restrict__ XSre,
                                                    ushort* __restrict__ XSim) {
  int p = threadIdx.x;
  int c = blockIdx.x, b = blockIdx.y;
  float mA = coef[p], mB = coef[PDIM+p], mC = coef[2*PDIM+p], mD = coef[3*PDIM+p], dts = coef[4*PDIM+p];
  size_t base = ((size_t)(b * LSEQ + c * TCH)) * PDIM + p;
  float4 cv = carries[((size_t)b * CHUNKS + c) * PDIM + p];
  float v1re = cv.x, v1im = cv.y, v2re = cv.z, v2im = cv.w;
  #pragma unroll 8
  for (int tt = 0; tt < TCH; tt++) {
    float fre = bf2f(F1re[base + (size_t)tt * PDIM]);
    float fim = bf2f(F1im[base + (size_t)tt * PDIM]);
    float n1re = fmaf(mA, v1re, fmaf(mB, v2re, fre));
    float n1im = fmaf(mA, v1im, fmaf(mB, v2im, fim));
    float n2re = fmaf(mC, v1re, fmaf(mD, v2re, dts * fre));
    float n2im = fmaf(mC, v1im, fmaf(mD, v2im, dts * fim));
    v1re = n1re; v1im = n1im; v2re = n2re; v2im = n2im;
    XSre[base + (size_t)tt * PDIM] = f2bf(v2re);
    XSim[base + (size_t)tt * PDIM] = f2bf(v2im);
  }
}

// ---------------- K4: out = XS . Wc + D*u via MFMA ----------------
__global__ __launch_bounds__(256) void out_mfma(const ushort* __restrict__ XSre,
                                                const ushort* __restrict__ XSim,
                                                const ushort* __restrict__ Wc,
                                                const float* __restrict__ u,
                                                const float* __restrict__ Dv,
                                                float* __restrict__ out) {
  int tid = threadIdx.x;
  int l = tid & 63, w = tid >> 6;
  int lr = l & 15, lk = l >> 4;
  int rowbase = blockIdx.x * 128 + w * 32;

  f32x4 acc[2][8];
  #pragma unroll
  for (int rt = 0; rt < 2; rt++)
    #pragma unroll
    for (int ct = 0; ct < 8; ct++)
      acc[rt][ct] = (f32x4){0.f, 0.f, 0.f, 0.f};

  #pragma unroll
  for (int kt = 0; kt < 16; kt++) {
    const ushort* XP = (kt < 8) ? XSre : XSim;
    int koff = (kt & 7)*32 + lk*8;
    bf16x8 afrag[2];
    #pragma unroll
    for (int rt = 0; rt < 2; rt++)
      afrag[rt] = *(const bf16x8*)(XP + (size_t)(rowbase + rt*16 + lr)*PDIM + koff);
    #pragma unroll
    for (int ct = 0; ct < 8; ct++) {
      bf16x8 b = *(const bf16x8*)(Wc + ((size_t)(ct*16 + kt)*64 + l)*8);
      acc[0][ct] = __builtin_amdgcn_mfma_f32_16x16x32_bf16(afrag[0], b, acc[0][ct], 0, 0, 0);
      acc[1][ct] = __builtin_amdgcn_mfma_f32_16x16x32_bf16(afrag[1], b, acc[1][ct], 0, 0, 0);
    }
  }

  #pragma unroll
  for (int rt = 0; rt < 2; rt++) {
    #pragma unroll
    for (int ct = 0; ct < 8; ct++) {
      int h = ct*16 + lr;
      float Dh = Dv[h];
      int r0 = rowbase + rt*16 + lk*4;
      f32x4 a = acc[rt][ct];
      #pragma unroll
      for (int r = 0; r < 4; r++) {
        size_t idx = (size_t)(r0 + r)*HDIM + h;
        out[idx] = a[r] + Dh * u[idx];
      }
    }
  }
}

extern "C" void kernel_launch(void* const* d_in, const int* in_sizes, int n_in,
                              void* d_out, int out_size, void* d_ws, size_t ws_size,
                              hipStream_t stream) {
  const float* u      = (const float*)d_in[0];
  const float* A_diag = (const float*)d_in[1];
  const float* G_diag = (const float*)d_in[2];
  const float* dt     = (const float*)d_in[3];
  const float* B      = (const float*)d_in[4];
  const float* C      = (const float*)d_in[5];
  const float* D      = (const float*)d_in[6];
  float* out = (float*)d_out;

  char* ws = (char*)d_ws;
  float*  coef    = (float*)(ws + WS_COEF);
  float*  mpow    = (float*)(ws + WS_MPOW);
  ushort* Wb      = (ushort*)(ws + WS_WB);
  ushort* Wc      = (ushort*)(ws + WS_WC);
  ushort* F1re    = (ushort*)(ws + WS_F1RE);
  ushort* F1im    = (ushort*)(ws + WS_F1IM);
  ushort* XSre    = (ushort*)(ws + WS_XSRE);
  ushort* XSim    = (ushort*)(ws + WS_XSIM);
  float4* ends    = (float4*)(ws + WS_ENDS);
  float4* carries = (float4*)(ws + WS_CARRY);

  hipLaunchKernelGGL(coeff_kernel, dim3(1), dim3(PDIM), 0, stream, A_diag, G_diag, dt, coef, mpow);
  hipLaunchKernelGGL(prep_kernel, dim3(512), dim3(256), 0, stream, B, C, coef, Wb, Wc);
  hipLaunchKernelGGL(bu_mfma, dim3(BLROWS/32), dim3(256), 0, stream, u, Wb, F1re, F1im);
  hipLaunchKernelGGL(scan1_kernel, dim3(CHUNKS, BSZ), dim3(256), 0, stream, F1re, F1im, coef, ends);
  hipLaunchKernelGGL(carry_kernel, dim3(BSZ), dim3(256), 0, stream, ends, mpow, carries);
  hipLaunchKernelGGL(scan2_kernel, dim3(CHUNKS, BSZ), dim3(256), 0, stream, F1re, F1im, coef, carries, XSre, XSim);
  hipLaunchKernelGGL(out_mfma, dim3(BLROWS/128), dim3(256), 0, stream, XSre, XSim, Wc, u, D, out);
}

// Round 3
// 164.454 us; speedup vs baseline: 3.1784x; 1.3562x over previous
//
#include <hip/hip_runtime.h>
#include <stdint.h>

#define BSZ   16
#define LSEQ  4096
#define HDIM  128
#define PDIM  256
#define TCH   32
#define CHUNKS (LSEQ/TCH)   // 128

typedef __attribute__((ext_vector_type(4))) float f32x4;
typedef __attribute__((ext_vector_type(8))) __bf16 bf16x8;

// ---------------- workspace layout (bytes) ----------------
constexpr size_t WS_COEF  = 0;                                      // 6*PDIM floats
constexpr size_t WS_MPOW2 = 8192;                                   // 7*4*PDIM floats (M^(32*2^j))
constexpr size_t WS_WB    = 40960;                                  // 128 KB frag-packed Wb
constexpr size_t WS_WC    = WS_WB + 131072;                         // 128 KB frag-packed Wc
constexpr size_t WS_ENDS  = WS_WC + 131072;                         // BSZ*CHUNKS*PDIM float4 = 8 MB
constexpr size_t WS_CARRY = WS_ENDS + (size_t)BSZ*CHUNKS*PDIM*16;   // 8 MB

__device__ __forceinline__ unsigned short f2bf(float f) {
  unsigned u = __float_as_uint(f);
  u = (u + 0x7fffu + ((u >> 16) & 1u)) >> 16;   // RNE
  return (unsigned short)u;
}
__device__ __forceinline__ float bf2f(unsigned short s) {
  return __uint_as_float(((unsigned)s) << 16);
}

// ---------------- K1: per-p coefficients + M^(32*2^j) powers ----------------
__global__ void coeff_kernel(const float* __restrict__ A_diag,
                             const float* __restrict__ G_diag,
                             const float* __restrict__ dtp,
                             float* __restrict__ coef,
                             float* __restrict__ mpow2) {
  int p = threadIdx.x;
  float dt_s = 1.0f / (1.0f + expf(-dtp[p]));
  float A = fmaxf(A_diag[p], 0.0f);
  float G = fmaxf(G_diag[p], 0.0f);
  float root  = sqrtf(1.0f + dt_s * G);
  float denom = fmaxf(dt_s * dt_s, 1e-6f);
  float A_low  = (2.0f + dt_s * G - 2.0f * root) / denom;
  float A_high = (2.0f + dt_s * G + 2.0f * root) / denom;
  A = A_low + fmaxf(A - A_low, 0.0f) - fmaxf(A - A_high, 0.0f);
  float S  = 1.0f / (1.0f + dt_s * G);
  float mA = S;
  float mB = -A * dt_s * S;
  float mC = dt_s * S;
  float mD = 1.0f - A * dt_s * dt_s * S;
  coef[0*PDIM + p] = mA;
  coef[1*PDIM + p] = mB;
  coef[2*PDIM + p] = mC;
  coef[3*PDIM + p] = mD;
  coef[4*PDIM + p] = dt_s;
  coef[5*PDIM + p] = mC;   // f1 scale = dt_s*S == mC
  float a = mA, b = mB, c = mC, d = mD;
  // 5 squarings -> M^32
  #pragma unroll
  for (int i = 0; i < 5; i++) {
    float na = a*a + b*c, nb = a*b + b*d, nc = c*a + d*c, nd = c*b + d*d;
    a = na; b = nb; c = nc; d = nd;
  }
  mpow2[(0*4+0)*PDIM + p] = a; mpow2[(0*4+1)*PDIM + p] = b;
  mpow2[(0*4+2)*PDIM + p] = c; mpow2[(0*4+3)*PDIM + p] = d;
  #pragma unroll
  for (int j = 1; j < 7; j++) {
    float na = a*a + b*c, nb = a*b + b*d, nc = c*a + d*c, nd = c*b + d*d;
    a = na; b = nb; c = nc; d = nd;
    mpow2[(j*4+0)*PDIM + p] = a; mpow2[(j*4+1)*PDIM + p] = b;
    mpow2[(j*4+2)*PDIM + p] = c; mpow2[(j*4+3)*PDIM + p] = d;
  }
}

// ---------------- K1b: pack weights in MFMA fragment order ----------------
__global__ __launch_bounds__(256) void prep_kernel(const float* __restrict__ B,
                                                   const float* __restrict__ C,
                                                   const float* __restrict__ coef,
                                                   ushort* __restrict__ Wb,
                                                   ushort* __restrict__ Wc) {
  int idx = blockIdx.x * 256 + threadIdx.x;   // 0..131071
  if (idx < 65536) {
    int e  = idx & 7;
    int l  = (idx >> 3) & 63;
    int kt = (idx >> 9) & 3;
    int ct = idx >> 11;
    int h   = kt*32 + (l >> 4)*8 + e;
    int col = ct*16 + (l & 15);
    int c = col >> 8, p = col & 255;
    float f1 = coef[5*PDIM + p];
    Wb[idx] = f2bf(B[(size_t)p*2*HDIM + h*2 + c] * f1);
  } else {
    int j  = idx - 65536;
    int e  = j & 7;
    int l  = (j >> 3) & 63;
    int kt = (j >> 9) & 15;
    int ct = j >> 13;
    int k = kt*32 + (l >> 4)*8 + e;
    int h = ct*16 + (l & 15);
    int c = k >> 8, p = k & 255;
    float v = C[(size_t)h*2*PDIM + p*2 + c];
    Wc[j] = f2bf(c ? -v : v);
  }
}

// ---------------- K_A: bu-GEMM (32x512, K=128) + chunk-local scan -> ends ----------------
__global__ __launch_bounds__(256) void ka_kernel(const float* __restrict__ u,
                                                 const ushort* __restrict__ Wb,
                                                 const float* __restrict__ coef,
                                                 float4* __restrict__ ends) {
  __shared__ ushort us[TCH][136];     // u chunk, bf16   (8.7 KB)
  __shared__ ushort f1t[512][36];     // F1^T [col][t]   (36.9 KB)
  int tid = threadIdx.x;
  int l = tid & 63, w = tid >> 6;
  int lr = l & 15, lk = l >> 4;
  int c = blockIdx.x, b = blockIdx.y;
  size_t row0 = (size_t)b * LSEQ + (size_t)c * TCH;

  // stage u -> bf16 LDS (coalesced 16 B/lane)
  #pragma unroll
  for (int rnd = 0; rnd < 4; rnd++) {
    int fidx = rnd * 256 + tid;              // float4 index, 0..1023
    int r = fidx >> 5, c4 = (fidx & 31) * 4;
    float4 f = *(const float4*)(u + (row0 + r) * HDIM + c4);
    ushort4 o = { f2bf(f.x), f2bf(f.y), f2bf(f.z), f2bf(f.w) };
    *(ushort4*)&us[r][c4] = o;
  }
  __syncthreads();

  // GEMM: wave w covers cols [w*128, w*128+128)
  f32x4 acc[2][8];
  #pragma unroll
  for (int rt = 0; rt < 2; rt++)
    #pragma unroll
    for (int ct = 0; ct < 8; ct++)
      acc[rt][ct] = (f32x4){0.f, 0.f, 0.f, 0.f};

  #pragma unroll
  for (int kt = 0; kt < 4; kt++) {
    bf16x8 af0 = *(const bf16x8*)&us[lr][kt*32 + lk*8];
    bf16x8 af1 = *(const bf16x8*)&us[16 + lr][kt*32 + lk*8];
    #pragma unroll
    for (int ct = 0; ct < 8; ct++) {
      int ctg = w*8 + ct;
      bf16x8 bfr = *(const bf16x8*)(Wb + ((size_t)(ctg*4 + kt)*64 + l)*8);
      acc[0][ct] = __builtin_amdgcn_mfma_f32_16x16x32_bf16(af0, bfr, acc[0][ct], 0, 0, 0);
      acc[1][ct] = __builtin_amdgcn_mfma_f32_16x16x32_bf16(af1, bfr, acc[1][ct], 0, 0, 0);
    }
  }
  // write F1^T to LDS: [col][t], 4 consecutive t per lane -> ds_write_b64
  #pragma unroll
  for (int rt = 0; rt < 2; rt++) {
    #pragma unroll
    for (int ct = 0; ct < 8; ct++) {
      int col = w*128 + ct*16 + lr;
      int t0 = rt*16 + lk*4;
      f32x4 a = acc[rt][ct];
      ushort4 v = { f2bf(a[0]), f2bf(a[1]), f2bf(a[2]), f2bf(a[3]) };
      *(ushort4*)&f1t[col][t0] = v;
    }
  }
  __syncthreads();

  // chunk-local scan (thread = p), zero init
  int p = tid;
  float mA = coef[p], mB = coef[PDIM+p], mC = coef[2*PDIM+p], mD = coef[3*PDIM+p], dts = coef[4*PDIM+p];
  float v1re = 0, v1im = 0, v2re = 0, v2im = 0;
  #pragma unroll
  for (int t4 = 0; t4 < TCH/4; t4++) {
    ushort4 fre4 = *(const ushort4*)&f1t[p][t4*4];
    ushort4 fim4 = *(const ushort4*)&f1t[p+256][t4*4];
    ushort fr[4] = {fre4.x, fre4.y, fre4.z, fre4.w};
    ushort fi[4] = {fim4.x, fim4.y, fim4.z, fim4.w};
    #pragma unroll
    for (int j = 0; j < 4; j++) {
      float fre = bf2f(fr[j]), fim = bf2f(fi[j]);
      float n1re = fmaf(mA, v1re, fmaf(mB, v2re, fre));
      float n1im = fmaf(mA, v1im, fmaf(mB, v2im, fim));
      float n2re = fmaf(mC, v1re, fmaf(mD, v2re, dts * fre));
      float n2im = fmaf(mC, v1im, fmaf(mD, v2im, dts * fim));
      v1re = n1re; v1im = n1im; v2re = n2re; v2im = n2im;
    }
  }
  ends[((size_t)b * CHUNKS + c) * PDIM + p] = make_float4(v1re, v1im, v2re, v2im);
}

// ---------------- K_carry: Kogge-Stone scan over 128 chunks ----------------
// block (b, pg): 256 threads = 128 chunks x 2 p
__global__ __launch_bounds__(256) void carry_kernel(const float4* __restrict__ ends,
                                                    const float* __restrict__ mpow2,
                                                    float4* __restrict__ carries) {
  __shared__ float4 buf[2][CHUNKS];
  int tid = threadIdx.x;
  int c = tid >> 1, pi = tid & 1;
  int b = blockIdx.x, pg = blockIdx.y;
  int p = pg * 2 + pi;
  size_t base = (size_t)b * CHUNKS * PDIM + p;
  float4 v = ends[base + (size_t)c * PDIM];
  buf[pi][c] = v;
  __syncthreads();
  #pragma unroll
  for (int j = 0; j < 7; j++) {
    int d = 1 << j;
    bool act = (c >= d);
    float4 s;
    if (act) s = buf[pi][c - d];
    __syncthreads();
    if (act) {
      float qA = mpow2[(j*4+0)*PDIM + p], qB = mpow2[(j*4+1)*PDIM + p];
      float qC = mpow2[(j*4+2)*PDIM + p], qD = mpow2[(j*4+3)*PDIM + p];
      v.x = fmaf(qA, s.x, fmaf(qB, s.z, v.x));
      v.y = fmaf(qA, s.y, fmaf(qB, s.w, v.y));
      v.z = fmaf(qC, s.x, fmaf(qD, s.z, v.z));
      v.w = fmaf(qC, s.y, fmaf(qD, s.w, v.w));
      buf[pi][c] = v;
    }
    __syncthreads();
  }
  float4 cv = (c == 0) ? make_float4(0.f, 0.f, 0.f, 0.f) : buf[pi][c - 1];
  carries[base + (size_t)c * PDIM] = cv;
}

// ---------------- K_B: bu-GEMM (recompute) + carry-in scan + out-GEMM ----------------
__global__ __launch_bounds__(256) void kb_kernel(const float* __restrict__ u,
                                                 const ushort* __restrict__ Wb,
                                                 const ushort* __restrict__ Wc,
                                                 const float* __restrict__ coef,
                                                 const float4* __restrict__ carries,
                                                 const float* __restrict__ Dv,
                                                 float* __restrict__ out) {
  // region A: us (phase1, 8704 B) overlapped by xst (phase2/3, 33280 B); region B: f1t (36864 B)
  __shared__ __align__(16) char smem[33280 + 36864];
  ushort (*us)[136]  = (ushort (*)[136])smem;
  ushort (*xst)[520] = (ushort (*)[520])smem;
  ushort (*f1t)[36]  = (ushort (*)[36])(smem + 33280);

  int tid = threadIdx.x;
  int l = tid & 63, w = tid >> 6;
  int lr = l & 15, lk = l >> 4;
  int c = blockIdx.x, b = blockIdx.y;
  size_t row0 = (size_t)b * LSEQ + (size_t)c * TCH;

  // ---- phase 1: stage u, bu-GEMM into f1t ----
  #pragma unroll
  for (int rnd = 0; rnd < 4; rnd++) {
    int fidx = rnd * 256 + tid;
    int r = fidx >> 5, c4 = (fidx & 31) * 4;
    float4 f = *(const float4*)(u + (row0 + r) * HDIM + c4);
    ushort4 o = { f2bf(f.x), f2bf(f.y), f2bf(f.z), f2bf(f.w) };
    *(ushort4*)&us[r][c4] = o;
  }
  __syncthreads();

  {
    f32x4 acc[2][8];
    #pragma unroll
    for (int rt = 0; rt < 2; rt++)
      #pragma unroll
      for (int ct = 0; ct < 8; ct++)
        acc[rt][ct] = (f32x4){0.f, 0.f, 0.f, 0.f};
    #pragma unroll
    for (int kt = 0; kt < 4; kt++) {
      bf16x8 af0 = *(const bf16x8*)&us[lr][kt*32 + lk*8];
      bf16x8 af1 = *(const bf16x8*)&us[16 + lr][kt*32 + lk*8];
      #pragma unroll
      for (int ct = 0; ct < 8; ct++) {
        int ctg = w*8 + ct;
        bf16x8 bfr = *(const bf16x8*)(Wb + ((size_t)(ctg*4 + kt)*64 + l)*8);
        acc[0][ct] = __builtin_amdgcn_mfma_f32_16x16x32_bf16(af0, bfr, acc[0][ct], 0, 0, 0);
        acc[1][ct] = __builtin_amdgcn_mfma_f32_16x16x32_bf16(af1, bfr, acc[1][ct], 0, 0, 0);
      }
    }
    __syncthreads();   // us fully consumed; xst region may now be written
    #pragma unroll
    for (int rt = 0; rt < 2; rt++) {
      #pragma unroll
      for (int ct = 0; ct < 8; ct++) {
        int col = w*128 + ct*16 + lr;
        int t0 = rt*16 + lk*4;
        f32x4 a = acc[rt][ct];
        ushort4 v = { f2bf(a[0]), f2bf(a[1]), f2bf(a[2]), f2bf(a[3]) };
        *(ushort4*)&f1t[col][t0] = v;
      }
    }
  }
  __syncthreads();

  // ---- phase 2: scan with carry-in, write xs rows into xst [t][re 256 | im 256] ----
  {
    int p = tid;
    float mA = coef[p], mB = coef[PDIM+p], mC = coef[2*PDIM+p], mD = coef[3*PDIM+p], dts = coef[4*PDIM+p];
    float4 cv = carries[((size_t)b * CHUNKS + c) * PDIM + p];
    float v1re = cv.x, v1im = cv.y, v2re = cv.z, v2im = cv.w;
    #pragma unroll
    for (int t4 = 0; t4 < TCH/4; t4++) {
      ushort4 fre4 = *(const ushort4*)&f1t[p][t4*4];
      ushort4 fim4 = *(const ushort4*)&f1t[p+256][t4*4];
      ushort fr[4] = {fre4.x, fre4.y, fre4.z, fre4.w};
      ushort fi[4] = {fim4.x, fim4.y, fim4.z, fim4.w};
      #pragma unroll
      for (int j = 0; j < 4; j++) {
        float fre = bf2f(fr[j]), fim = bf2f(fi[j]);
        float n1re = fmaf(mA, v1re, fmaf(mB, v2re, fre));
        float n1im = fmaf(mA, v1im, fmaf(mB, v2im, fim));
        float n2re = fmaf(mC, v1re, fmaf(mD, v2re, dts * fre));
        float n2im = fmaf(mC, v1im, fmaf(mD, v2im, dts * fim));
        v1re = n1re; v1im = n1im; v2re = n2re; v2im = n2im;
        int t = t4*4 + j;
        xst[t][p]       = f2bf(v2re);
        xst[t][p + 256] = f2bf(v2im);
      }
    }
  }
  __syncthreads();

  // ---- phase 3: out-GEMM (32 x 128, K=512) + D*u epilogue ----
  {
    int rt = w & 1;
    int cg = (w >> 1) * 4;
    f32x4 oacc[4];
    #pragma unroll
    for (int i = 0; i < 4; i++) oacc[i] = (f32x4){0.f, 0.f, 0.f, 0.f};
    #pragma unroll
    for (int kt = 0; kt < 16; kt++) {
      bf16x8 af = *(const bf16x8*)&xst[rt*16 + lr][kt*32 + lk*8];
      #pragma unroll
      for (int i = 0; i < 4; i++) {
        bf16x8 bfr = *(const bf16x8*)(Wc + ((size_t)((cg+i)*16 + kt)*64 + l)*8);
        oacc[i] = __builtin_amdgcn_mfma_f32_16x16x32_bf16(af, bfr, oacc[i], 0, 0, 0);
      }
    }
    #pragma unroll
    for (int i = 0; i < 4; i++) {
      int h = (cg+i)*16 + lr;
      float Dh = Dv[h];
      #pragma unroll
      for (int r = 0; r < 4; r++) {
        int t = rt*16 + lk*4 + r;
        size_t idx = (row0 + t) * HDIM + h;
        out[idx] = oacc[i][r] + Dh * u[idx];
      }
    }
  }
}

extern "C" void kernel_launch(void* const* d_in, const int* in_sizes, int n_in,
                              void* d_out, int out_size, void* d_ws, size_t ws_size,
                              hipStream_t stream) {
  const float* u      = (const float*)d_in[0];
  const float* A_diag = (const float*)d_in[1];
  const float* G_diag = (const float*)d_in[2];
  const float* dt     = (const float*)d_in[3];
  const float* B      = (const float*)d_in[4];
  const float* C      = (const float*)d_in[5];
  const float* D      = (const float*)d_in[6];
  float* out = (float*)d_out;

  char* ws = (char*)d_ws;
  float*  coef    = (float*)(ws + WS_COEF);
  float*  mpow2   = (float*)(ws + WS_MPOW2);
  ushort* Wb      = (ushort*)(ws + WS_WB);
  ushort* Wc      = (ushort*)(ws + WS_WC);
  float4* ends    = (float4*)(ws + WS_ENDS);
  float4* carries = (float4*)(ws + WS_CARRY);

  hipLaunchKernelGGL(coeff_kernel, dim3(1), dim3(PDIM), 0, stream, A_diag, G_diag, dt, coef, mpow2);
  hipLaunchKernelGGL(prep_kernel, dim3(512), dim3(256), 0, stream, B, C, coef, Wb, Wc);
  hipLaunchKernelGGL(ka_kernel, dim3(CHUNKS, BSZ), dim3(256), 0, stream, u, Wb, coef, ends);
  hipLaunchKernelGGL(carry_kernel, dim3(BSZ, PDIM/2), dim3(256), 0, stream, ends, mpow2, carries);
  hipLaunchKernelGGL(kb_kernel, dim3(CHUNKS, BSZ), dim3(256), 0, stream, u, Wb, Wc, coef, carries, D, out);
}